// Round 5
// baseline (74.760 us; speedup 1.0000x reference)
//
#include <hip/hip_runtime.h>
#include <hip/hip_bf16.h>
#include <math.h>

constexpr int D_MODEL  = 256;
constexpr int N_HEADS  = 8;

typedef __attribute__((ext_vector_type(8))) short bf16x8;
typedef __attribute__((ext_vector_type(4))) float f32x4;

__device__ __forceinline__ void gld_lds16(const void* gsrc, void* ldst) {
    __builtin_amdgcn_global_load_lds(
        (const __attribute__((address_space(1))) unsigned int*)gsrc,
        (__attribute__((address_space(3))) unsigned int*)ldst, 16, 0, 0);
}

// ---------------------------------------------------------------------------
// Convert query -> bf16 [M][256]; pack W_off|W_attn|W_out transposed into
// Wt[640][256] bf16; transpose value -> vt[h][pix][32] f32 (head-major).
// ---------------------------------------------------------------------------
__global__ __launch_bounds__(256) void convert_kernel(
    const float* __restrict__ q,
    const float* __restrict__ Woff,
    const float* __restrict__ Wattn,
    const float* __restrict__ Wout,
    const float* __restrict__ value,
    __hip_bfloat16* __restrict__ qbf,
    __hip_bfloat16* __restrict__ wt,
    float* __restrict__ vt,
    int M, int Lv)
{
    int t = blockIdx.x * 256 + threadIdx.x;
    int nq4 = M * 64;                       // float4 count of query
    if (t < nq4) {
        float4 v = reinterpret_cast<const float4*>(q)[t];
        union { __hip_bfloat16 h[4]; ushort4 u; } cv;
        cv.h[0] = __float2bfloat16(v.x);
        cv.h[1] = __float2bfloat16(v.y);
        cv.h[2] = __float2bfloat16(v.z);
        cv.h[3] = __float2bfloat16(v.w);
        reinterpret_cast<ushort4*>(qbf)[t] = cv.u;
        return;
    }
    int t2 = t - nq4;
    if (t2 < 640 * 256) {
        int c = t2 >> 8, k = t2 & 255;
        float val = (c < 256) ? Woff[k * 256 + c]
                  : (c < 384) ? Wattn[k * 128 + (c - 256)]
                              : Wout[k * 256 + (c - 384)];
        wt[c * 256 + k] = __float2bfloat16(val);
        return;
    }
    int t3 = t2 - 640 * 256;                // float4 index into value
    if (t3 < Lv * 64) {
        int pix = t3 >> 6;
        int c4  = (t3 & 63) * 4;            // channel 0..252 step 4
        int h   = c4 >> 5, d = c4 & 31;
        float4 v = reinterpret_cast<const float4*>(value)[t3];
        *reinterpret_cast<float4*>(vt + (size_t)h * Lv * 32 + (size_t)pix * 32 + d) = v;
    }
}

// ---------------------------------------------------------------------------
// bf16 MFMA GEMM (unchanged from R4): BM=128, BN=64, BK=64, 4 waves,
// 16x16x32 bf16, global_load_lds staging with both-sides XOR swizzle.
// EPI=0: out0 = acc + ba.  EPI=1: n0<256 -> loc epilogue; else softmax.
// ---------------------------------------------------------------------------
template <int EPI>
__global__ __launch_bounds__(256) void gemm_mfma(
    const __hip_bfloat16* __restrict__ Abf,
    const __hip_bfloat16* __restrict__ Wt,
    int wrow0,
    const float* __restrict__ ba,
    const float* __restrict__ bb,
    const float* __restrict__ refpts,
    float* __restrict__ out0,
    float* __restrict__ out1,
    int M)
{
    __shared__ __align__(16) char smem[128 * 68 * 4];   // 34816B
    char*  A_lds = smem;            // [128 rows][128B]  (16KB)
    char*  B_lds = smem + 16384;    // [64 rows][128B]   (8KB)
    float* C_lds = (float*)smem;    // [128][68] f32 (unioned, post-loop)

    const int tid = threadIdx.x;
    const int w = tid >> 6, l = tid & 63;
    const int m0 = blockIdx.y * 128;
    const int n0 = blockIdx.x * 64;

    const char* Asrc = (const char*)Abf;                                  // 512B rows
    const char* Wsrc = (const char*)(Wt + (size_t)(wrow0 + n0) * 256);    // 512B rows

    f32x4 acc[2][4] = {};

    const int lr8 = l >> 3, l7 = l & 7;

    for (int k0 = 0; k0 < 512; k0 += 128) {
#pragma unroll
        for (int i = 0; i < 4; ++i) {
            int chunk = (w << 2) + i;
            int row = (chunk << 3) + lr8;
            int m = m0 + row; m = m < M ? m : (M - 1);
            gld_lds16(Asrc + (size_t)m * 512 + k0 + ((l7 ^ (row & 7)) << 4),
                      A_lds + (chunk << 10));
        }
#pragma unroll
        for (int i = 0; i < 2; ++i) {
            int chunk = (w << 1) + i;
            int row = (chunk << 3) + lr8;
            gld_lds16(Wsrc + (size_t)row * 512 + k0 + ((l7 ^ (row & 7)) << 4),
                      B_lds + (chunk << 10));
        }
        __syncthreads();

#pragma unroll
        for (int kk = 0; kk < 2; ++kk) {
            bf16x8 av[2], bv[4];
#pragma unroll
            for (int mf = 0; mf < 2; ++mf) {
                int arow = (w << 5) + (mf << 4) + (l & 15);
                int acb = ((kk << 6) + ((l >> 4) << 4)) ^ ((arow & 7) << 4);
                av[mf] = *(const bf16x8*)(A_lds + arow * 128 + acb);
            }
#pragma unroll
            for (int nf = 0; nf < 4; ++nf) {
                int brow = (nf << 4) + (l & 15);
                int bcb = ((kk << 6) + ((l >> 4) << 4)) ^ ((brow & 7) << 4);
                bv[nf] = *(const bf16x8*)(B_lds + brow * 128 + bcb);
            }
#pragma unroll
            for (int mf = 0; mf < 2; ++mf)
#pragma unroll
                for (int nf = 0; nf < 4; ++nf)
                    acc[mf][nf] = __builtin_amdgcn_mfma_f32_16x16x32_bf16(
                        av[mf], bv[nf], acc[mf][nf], 0, 0, 0);
        }
        __syncthreads();
    }

#pragma unroll
    for (int mf = 0; mf < 2; ++mf)
#pragma unroll
        for (int nf = 0; nf < 4; ++nf) {
            int col = (nf << 4) + (l & 15);
            int rbase = (w << 5) + (mf << 4) + ((l >> 4) << 2);
#pragma unroll
            for (int j = 0; j < 4; ++j)
                C_lds[(rbase + j) * 68 + col] = acc[mf][nf][j];
        }
    __syncthreads();

    if (EPI == 0 || n0 < 256) {
#pragma unroll
        for (int r2 = 0; r2 < 2; ++r2) {
            int row = (r2 << 6) + (tid >> 2);
            int q = m0 + row;
            if (q >= M) continue;
            float rx = 0.f, ry = 0.f;
            if (EPI == 1) { rx = refpts[q * 2]; ry = refpts[q * 2 + 1]; }
#pragma unroll
            for (int g = 0; g < 4; ++g) {
                int col = ((tid & 3) << 4) + (g << 2);
                float4 v  = *(float4*)&C_lds[row * 68 + col];
                float4 b4 = *(const float4*)&ba[n0 + col];
                if (EPI == 0) {
                    v.x += b4.x; v.y += b4.y; v.z += b4.z; v.w += b4.w;
                } else {
                    int c = n0 + col;                        // h*32+l*8+p*2+xy
                    float rn = 1.0f / (float)(96 >> ((c >> 3) & 3));
                    v.x = rx + (v.x + b4.x) * rn;
                    v.y = ry + (v.y + b4.y) * rn;
                    v.z = rx + (v.z + b4.z) * rn;
                    v.w = ry + (v.w + b4.w) * rn;
                }
                *(float4*)&out0[(size_t)q * 256 + n0 + col] = v;
            }
        }
    } else {
        for (int u = tid; u < 512; u += 256) {
            int row = u >> 2, hh = u & 3;
            int q = m0 + row;
            if (q >= M) continue;
            int cg = (n0 - 256) + (hh << 4);
            float s[16];
            float mx = -1e30f;
#pragma unroll
            for (int i = 0; i < 16; ++i) {
                s[i] = C_lds[row * 68 + (hh << 4) + i] + bb[cg + i];
                mx = fmaxf(mx, s[i]);
            }
            float sum = 0.f;
#pragma unroll
            for (int i = 0; i < 16; ++i) { s[i] = __expf(s[i] - mx); sum += s[i]; }
            float inv = 1.0f / sum;
#pragma unroll
            for (int g = 0; g < 4; ++g) {
                float4 v = make_float4(s[g*4]*inv, s[g*4+1]*inv, s[g*4+2]*inv, s[g*4+3]*inv);
                *(float4*)&out1[(size_t)q * 128 + cg + (g << 2)] = v;
            }
        }
    }
}

// ---------------------------------------------------------------------------
// Deformable bilinear sampling, head-major value, head-grouped blocks.
// Block b: head h = b&7 (XCD-affine via round-robin dispatch), 32 consecutive
// q's. 8 lanes per (q,h) unit; lane owns 4 dims. Per-head working set is
// 1.57 MB -> fits one XCD's 4 MiB L2.
// ---------------------------------------------------------------------------
__global__ __launch_bounds__(256, 8) void sample_kernel(
    const float* __restrict__ loc,
    const float* __restrict__ attn,
    const float* __restrict__ vt,      // [8][Lv][32] f32, head-major
    __hip_bfloat16* __restrict__ core, // [M][256] bf16
    int M, int Lv)
{
    const int h    = blockIdx.x & 7;
    const int q0   = (blockIdx.x >> 3) << 5;     // 32 q's per block
    const int unit = threadIdx.x >> 3;           // 0..31
    const int d4   = threadIdx.x & 7;
    const int q    = q0 + unit;
    if (q >= M) return;

    const float4* locq4 = reinterpret_cast<const float4*>(loc  + (size_t)q * 256 + h * 32);
    const float4* attq4 = reinterpret_cast<const float4*>(attn + (size_t)q * 128 + h * 16);
    const float*  plane = vt + (size_t)h * Lv * 32 + d4 * 4;

    float4 acc = make_float4(0.f, 0.f, 0.f, 0.f);

#pragma unroll 1
    for (int lvl = 0; lvl < 4; ++lvl) {
        const int Wl = 96 >> lvl;                        // H == W per level
        const int start = 12288 - (12288 >> (2 * lvl));  // 0,9216,11520,12096
        const float fW = (float)Wl;
        const int rowstride = Wl * 32;
        const float* feat = plane + (size_t)start * 32;

        float4 lp0 = locq4[lvl * 2 + 0];
        float4 lp1 = locq4[lvl * 2 + 1];
        float4 aw  = attq4[lvl];

        const float lxs[4] = {lp0.x, lp0.z, lp1.x, lp1.z};
        const float lys[4] = {lp0.y, lp0.w, lp1.y, lp1.w};
        const float aws[4] = {aw.x, aw.y, aw.z, aw.w};

#pragma unroll
        for (int p = 0; p < 4; ++p) {
            float x = lxs[p] * fW - 0.5f;
            float y = lys[p] * fW - 0.5f;
            float wgt = aws[p];

            float x0f = floorf(x);
            float y0f = floorf(y);
            float wx1 = x - x0f, wy1 = y - y0f;
            float wx0 = 1.f - wx1, wy0 = 1.f - wy1;
            int ix = (int)x0f;
            int iy = (int)y0f;

            float wxv0 = ((unsigned)ix       < (unsigned)Wl) ? wx0 : 0.f;
            float wxv1 = ((unsigned)(ix + 1) < (unsigned)Wl) ? wx1 : 0.f;
            float wyv0 = (((unsigned)iy       < (unsigned)Wl) ? wy0 : 0.f) * wgt;
            float wyv1 = (((unsigned)(iy + 1) < (unsigned)Wl) ? wy1 : 0.f) * wgt;

            int ix0 = min(max(ix,     0), Wl - 1);
            int ix1 = min(max(ix + 1, 0), Wl - 1);
            int iy0 = min(max(iy,     0), Wl - 1);
            int iy1 = min(max(iy + 1, 0), Wl - 1);

            const float* row0 = feat + (size_t)iy0 * rowstride;
            const float* row1 = feat + (size_t)iy1 * rowstride;
            float4 v00 = *reinterpret_cast<const float4*>(&row0[ix0 * 32]);
            float4 v10 = *reinterpret_cast<const float4*>(&row0[ix1 * 32]);
            float4 v01 = *reinterpret_cast<const float4*>(&row1[ix0 * 32]);
            float4 v11 = *reinterpret_cast<const float4*>(&row1[ix1 * 32]);

            float w00 = wxv0 * wyv0, w10 = wxv1 * wyv0;
            float w01 = wxv0 * wyv1, w11 = wxv1 * wyv1;

            acc.x = fmaf(v00.x, w00, acc.x); acc.x = fmaf(v10.x, w10, acc.x);
            acc.x = fmaf(v01.x, w01, acc.x); acc.x = fmaf(v11.x, w11, acc.x);
            acc.y = fmaf(v00.y, w00, acc.y); acc.y = fmaf(v10.y, w10, acc.y);
            acc.y = fmaf(v01.y, w01, acc.y); acc.y = fmaf(v11.y, w11, acc.y);
            acc.z = fmaf(v00.z, w00, acc.z); acc.z = fmaf(v10.z, w10, acc.z);
            acc.z = fmaf(v01.z, w01, acc.z); acc.z = fmaf(v11.z, w11, acc.z);
            acc.w = fmaf(v00.w, w00, acc.w); acc.w = fmaf(v10.w, w10, acc.w);
            acc.w = fmaf(v01.w, w01, acc.w); acc.w = fmaf(v11.w, w11, acc.w);
        }
    }

    union { __hip_bfloat16 h4[4]; ushort4 u4; } st;
    st.h4[0] = __float2bfloat16(acc.x);
    st.h4[1] = __float2bfloat16(acc.y);
    st.h4[2] = __float2bfloat16(acc.z);
    st.h4[3] = __float2bfloat16(acc.w);
    *reinterpret_cast<ushort4*>(core + ((size_t)q * 256 + h * 32 + d4 * 4)) = st.u4;
}

// ---------------------------------------------------------------------------
extern "C" void kernel_launch(void* const* d_in, const int* in_sizes, int n_in,
                              void* d_out, int out_size, void* d_ws, size_t ws_size,
                              hipStream_t stream)
{
    const float* query  = (const float*)d_in[0];
    const float* refp   = (const float*)d_in[1];
    const float* value  = (const float*)d_in[2];
    const float* W_off  = (const float*)d_in[5];
    const float* b_off  = (const float*)d_in[6];
    const float* W_attn = (const float*)d_in[7];
    const float* b_attn = (const float*)d_in[8];
    const float* W_out  = (const float*)d_in[9];
    const float* b_out  = (const float*)d_in[10];
    float* out = (float*)d_out;

    const int M  = in_sizes[0] / D_MODEL;   // 12240
    const int Lv = in_sizes[2] / D_MODEL;   // 12240

    // workspace layout (~38 MB)
    float* loc  = (float*)d_ws;                                      // M*256 f32
    float* attn = loc + (size_t)M * 256;                             // M*128 f32
    __hip_bfloat16* qbf = (__hip_bfloat16*)(attn + (size_t)M * 128); // M*256 bf16
    __hip_bfloat16* wt  = qbf + (size_t)M * 256;                     // 640*256 bf16
    float* vt = (float*)(wt + 640 * 256);                            // 8*Lv*32 f32
    __hip_bfloat16* core = qbf;   // alias: qbf dead after stage 1

    dim3 blk(256);
    const int mblocks = (M + 127) / 128;

    // Stage 0: bf16 conversion + weight pack + value head-major transpose
    int convthreads = M * 64 + 640 * 256 + Lv * 64;
    hipLaunchKernelGGL(convert_kernel, dim3((convthreads + 255) / 256), blk, 0, stream,
                       query, W_off, W_attn, W_out, value, qbf, wt, vt, M, Lv);

    // Stage 1: offsets+attention GEMM (N=384) with loc/softmax epilogue
    hipLaunchKernelGGL((gemm_mfma<1>), dim3(6, mblocks), blk, 0, stream,
                       qbf, wt, 0, b_off, b_attn, refp, loc, attn, M);

    // Stage 2: deformable bilinear sampling -> core (bf16, overwrites qbf)
    const int qchunks = (M + 31) / 32;
    hipLaunchKernelGGL(sample_kernel, dim3(qchunks * 8), blk, 0, stream,
                       loc, attn, vt, core, M, Lv);

    // Stage 3: output projection (N=256)
    hipLaunchKernelGGL((gemm_mfma<0>), dim3(4, mblocks), blk, 0, stream,
                       core, wt, 384, b_out, nullptr, nullptr, out, nullptr, M);
}

// Round 7
// 68.211 us; speedup vs baseline: 1.0960x; 1.0960x over previous
//
#include <hip/hip_runtime.h>
#include <hip/hip_bf16.h>
#include <math.h>

constexpr int D_MODEL  = 256;
constexpr int N_HEADS  = 8;

typedef __attribute__((ext_vector_type(8))) short bf16x8;
typedef __attribute__((ext_vector_type(4))) float f32x4;

__device__ __forceinline__ void gld_lds16(const void* gsrc, void* ldst) {
    __builtin_amdgcn_global_load_lds(
        (const __attribute__((address_space(1))) unsigned int*)gsrc,
        (__attribute__((address_space(3))) unsigned int*)ldst, 16, 0, 0);
}

// ---------------------------------------------------------------------------
// Convert query -> bf16 [M][256]; pack W_off|W_attn|W_out transposed into
// Wt[640][256] bf16; transpose value -> vt[h][pix][32] BF16 (head-major).
// ---------------------------------------------------------------------------
__global__ __launch_bounds__(256) void convert_kernel(
    const float* __restrict__ q,
    const float* __restrict__ Woff,
    const float* __restrict__ Wattn,
    const float* __restrict__ Wout,
    const float* __restrict__ value,
    __hip_bfloat16* __restrict__ qbf,
    __hip_bfloat16* __restrict__ wt,
    __hip_bfloat16* __restrict__ vt,
    int M, int Lv)
{
    int t = blockIdx.x * 256 + threadIdx.x;
    int nq4 = M * 64;                       // float4 count of query
    if (t < nq4) {
        float4 v = reinterpret_cast<const float4*>(q)[t];
        union { __hip_bfloat16 h[4]; ushort4 u; } cv;
        cv.h[0] = __float2bfloat16(v.x);
        cv.h[1] = __float2bfloat16(v.y);
        cv.h[2] = __float2bfloat16(v.z);
        cv.h[3] = __float2bfloat16(v.w);
        reinterpret_cast<ushort4*>(qbf)[t] = cv.u;
        return;
    }
    int t2 = t - nq4;
    if (t2 < 640 * 256) {
        int c = t2 >> 8, k = t2 & 255;
        float val = (c < 256) ? Woff[k * 256 + c]
                  : (c < 384) ? Wattn[k * 128 + (c - 256)]
                              : Wout[k * 256 + (c - 384)];
        wt[c * 256 + k] = __float2bfloat16(val);
        return;
    }
    int t3 = t2 - 640 * 256;                // float4 index into value
    if (t3 < Lv * 64) {
        int pix = t3 >> 6;
        int c4  = (t3 & 63) * 4;            // channel 0..252 step 4
        int h   = c4 >> 5, d = c4 & 31;
        float4 v = reinterpret_cast<const float4*>(value)[t3];
        union { __hip_bfloat16 h4[4]; ushort4 u; } cv;
        cv.h4[0] = __float2bfloat16(v.x);
        cv.h4[1] = __float2bfloat16(v.y);
        cv.h4[2] = __float2bfloat16(v.z);
        cv.h4[3] = __float2bfloat16(v.w);
        *reinterpret_cast<ushort4*>(vt + (size_t)h * Lv * 32 + (size_t)pix * 32 + d) = cv.u;
    }
}

// ---------------------------------------------------------------------------
// bf16 MFMA GEMM (unchanged from R4): BM=128, BN=64, BK=64, 4 waves,
// 16x16x32 bf16, global_load_lds staging with both-sides XOR swizzle.
// EPI=0: out0 = acc + ba.  EPI=1: n0<256 -> loc epilogue; else softmax.
// ---------------------------------------------------------------------------
template <int EPI>
__global__ __launch_bounds__(256) void gemm_mfma(
    const __hip_bfloat16* __restrict__ Abf,
    const __hip_bfloat16* __restrict__ Wt,
    int wrow0,
    const float* __restrict__ ba,
    const float* __restrict__ bb,
    const float* __restrict__ refpts,
    float* __restrict__ out0,
    float* __restrict__ out1,
    int M)
{
    __shared__ __align__(16) char smem[128 * 68 * 4];   // 34816B
    char*  A_lds = smem;            // [128 rows][128B]  (16KB)
    char*  B_lds = smem + 16384;    // [64 rows][128B]   (8KB)
    float* C_lds = (float*)smem;    // [128][68] f32 (unioned, post-loop)

    const int tid = threadIdx.x;
    const int w = tid >> 6, l = tid & 63;
    const int m0 = blockIdx.y * 128;
    const int n0 = blockIdx.x * 64;

    const char* Asrc = (const char*)Abf;                                  // 512B rows
    const char* Wsrc = (const char*)(Wt + (size_t)(wrow0 + n0) * 256);    // 512B rows

    f32x4 acc[2][4] = {};

    const int lr8 = l >> 3, l7 = l & 7;

    for (int k0 = 0; k0 < 512; k0 += 128) {
#pragma unroll
        for (int i = 0; i < 4; ++i) {
            int chunk = (w << 2) + i;
            int row = (chunk << 3) + lr8;
            int m = m0 + row; m = m < M ? m : (M - 1);
            gld_lds16(Asrc + (size_t)m * 512 + k0 + ((l7 ^ (row & 7)) << 4),
                      A_lds + (chunk << 10));
        }
#pragma unroll
        for (int i = 0; i < 2; ++i) {
            int chunk = (w << 1) + i;
            int row = (chunk << 3) + lr8;
            gld_lds16(Wsrc + (size_t)row * 512 + k0 + ((l7 ^ (row & 7)) << 4),
                      B_lds + (chunk << 10));
        }
        __syncthreads();

#pragma unroll
        for (int kk = 0; kk < 2; ++kk) {
            bf16x8 av[2], bv[4];
#pragma unroll
            for (int mf = 0; mf < 2; ++mf) {
                int arow = (w << 5) + (mf << 4) + (l & 15);
                int acb = ((kk << 6) + ((l >> 4) << 4)) ^ ((arow & 7) << 4);
                av[mf] = *(const bf16x8*)(A_lds + arow * 128 + acb);
            }
#pragma unroll
            for (int nf = 0; nf < 4; ++nf) {
                int brow = (nf << 4) + (l & 15);
                int bcb = ((kk << 6) + ((l >> 4) << 4)) ^ ((brow & 7) << 4);
                bv[nf] = *(const bf16x8*)(B_lds + brow * 128 + bcb);
            }
#pragma unroll
            for (int mf = 0; mf < 2; ++mf)
#pragma unroll
                for (int nf = 0; nf < 4; ++nf)
                    acc[mf][nf] = __builtin_amdgcn_mfma_f32_16x16x32_bf16(
                        av[mf], bv[nf], acc[mf][nf], 0, 0, 0);
        }
        __syncthreads();
    }

#pragma unroll
    for (int mf = 0; mf < 2; ++mf)
#pragma unroll
        for (int nf = 0; nf < 4; ++nf) {
            int col = (nf << 4) + (l & 15);
            int rbase = (w << 5) + (mf << 4) + ((l >> 4) << 2);
#pragma unroll
            for (int j = 0; j < 4; ++j)
                C_lds[(rbase + j) * 68 + col] = acc[mf][nf][j];
        }
    __syncthreads();

    if (EPI == 0 || n0 < 256) {
#pragma unroll
        for (int r2 = 0; r2 < 2; ++r2) {
            int row = (r2 << 6) + (tid >> 2);
            int q = m0 + row;
            if (q >= M) continue;
            float rx = 0.f, ry = 0.f;
            if (EPI == 1) { rx = refpts[q * 2]; ry = refpts[q * 2 + 1]; }
#pragma unroll
            for (int g = 0; g < 4; ++g) {
                int col = ((tid & 3) << 4) + (g << 2);
                float4 v  = *(float4*)&C_lds[row * 68 + col];
                float4 b4 = *(const float4*)&ba[n0 + col];
                if (EPI == 0) {
                    v.x += b4.x; v.y += b4.y; v.z += b4.z; v.w += b4.w;
                } else {
                    int c = n0 + col;                        // h*32+l*8+p*2+xy
                    float rn = 1.0f / (float)(96 >> ((c >> 3) & 3));
                    v.x = rx + (v.x + b4.x) * rn;
                    v.y = ry + (v.y + b4.y) * rn;
                    v.z = rx + (v.z + b4.z) * rn;
                    v.w = ry + (v.w + b4.w) * rn;
                }
                *(float4*)&out0[(size_t)q * 256 + n0 + col] = v;
            }
        }
    } else {
        for (int u = tid; u < 512; u += 256) {
            int row = u >> 2, hh = u & 3;
            int q = m0 + row;
            if (q >= M) continue;
            int cg = (n0 - 256) + (hh << 4);
            float s[16];
            float mx = -1e30f;
#pragma unroll
            for (int i = 0; i < 16; ++i) {
                s[i] = C_lds[row * 68 + (hh << 4) + i] + bb[cg + i];
                mx = fmaxf(mx, s[i]);
            }
            float sum = 0.f;
#pragma unroll
            for (int i = 0; i < 16; ++i) { s[i] = __expf(s[i] - mx); sum += s[i]; }
            float inv = 1.0f / sum;
#pragma unroll
            for (int g = 0; g < 4; ++g) {
                float4 v = make_float4(s[g*4]*inv, s[g*4+1]*inv, s[g*4+2]*inv, s[g*4+3]*inv);
                *(float4*)&out1[(size_t)q * 128 + cg + (g << 2)] = v;
            }
        }
    }
}

// ---------------------------------------------------------------------------
// ds_swizzle helpers with template-parameter immediates (frontend ICE req.)
// ---------------------------------------------------------------------------
template <int IMM>
__device__ __forceinline__ float swzf(float v) {
    return __int_as_float(__builtin_amdgcn_ds_swizzle(__float_as_int(v), IMM));
}
template <int IMM>
__device__ __forceinline__ int swzi(int v) {
    return __builtin_amdgcn_ds_swizzle(v, IMM);
}

// One sampling point P (0..15): pull weights/offsets from owner lane P>>1
// (bit-mode imm: and=0x18 keeps lane bits[4:3], or=owner sets bits[2:0]),
// gather 4 bf16 corners (8B each), accumulate.
template <int P>
__device__ __forceinline__ void do_point(
    const float wv[2][4], const int ov[2][4], const char* planeB,
    float& a0, float& a1, float& a2, float& a3)
{
    constexpr int S   = P & 1;
    constexpr int IMM = ((P >> 1) << 5) | 0x18;

    float w00 = swzf<IMM>(wv[S][0]);
    float w10 = swzf<IMM>(wv[S][1]);
    float w01 = swzf<IMM>(wv[S][2]);
    float w11 = swzf<IMM>(wv[S][3]);
    int o00 = swzi<IMM>(ov[S][0]);
    int o10 = swzi<IMM>(ov[S][1]);
    int o01 = swzi<IMM>(ov[S][2]);
    int o11 = swzi<IMM>(ov[S][3]);

    uint2 u00 = *(const uint2*)(planeB + o00);
    uint2 u10 = *(const uint2*)(planeB + o10);
    uint2 u01 = *(const uint2*)(planeB + o01);
    uint2 u11 = *(const uint2*)(planeB + o11);

    a0 = fmaf(__uint_as_float(u00.x << 16),         w00, a0);
    a1 = fmaf(__uint_as_float(u00.x & 0xffff0000u), w00, a1);
    a2 = fmaf(__uint_as_float(u00.y << 16),         w00, a2);
    a3 = fmaf(__uint_as_float(u00.y & 0xffff0000u), w00, a3);
    a0 = fmaf(__uint_as_float(u10.x << 16),         w10, a0);
    a1 = fmaf(__uint_as_float(u10.x & 0xffff0000u), w10, a1);
    a2 = fmaf(__uint_as_float(u10.y << 16),         w10, a2);
    a3 = fmaf(__uint_as_float(u10.y & 0xffff0000u), w10, a3);
    a0 = fmaf(__uint_as_float(u01.x << 16),         w01, a0);
    a1 = fmaf(__uint_as_float(u01.x & 0xffff0000u), w01, a1);
    a2 = fmaf(__uint_as_float(u01.y << 16),         w01, a2);
    a3 = fmaf(__uint_as_float(u01.y & 0xffff0000u), w01, a3);
    a0 = fmaf(__uint_as_float(u11.x << 16),         w11, a0);
    a1 = fmaf(__uint_as_float(u11.x & 0xffff0000u), w11, a1);
    a2 = fmaf(__uint_as_float(u11.y << 16),         w11, a2);
    a3 = fmaf(__uint_as_float(u11.y & 0xffff0000u), w11, a3);
}

// ---------------------------------------------------------------------------
// Deformable bilinear sampling v3: bf16 head-major value + ds_swizzle-shared
// coordinate math. Unit = 8 lanes = one (q,h). Lane k computes coords for
// points {2k, 2k+1} (level k>>1). Corner load = 8B (4 bf16 dims/lane).
// ---------------------------------------------------------------------------
__global__ __launch_bounds__(256, 8) void sample_kernel(
    const float* __restrict__ loc,
    const float* __restrict__ attn,
    const __hip_bfloat16* __restrict__ vt, // [8][Lv][32] bf16, head-major
    __hip_bfloat16* __restrict__ core,     // [M][256] bf16
    int M, int Lv)
{
    const int h    = blockIdx.x & 7;
    const int q0   = (blockIdx.x >> 3) << 5;     // 32 q's per block
    const int unit = threadIdx.x >> 3;           // 0..31
    const int k    = threadIdx.x & 7;            // lane-in-unit
    const int q    = q0 + unit;
    if (q >= M) return;                          // whole 8-lane units exit

    // ---- owner phase: lane k -> points 2k, 2k+1 (level lvl = k>>1) ----
    const int lvl   = k >> 1;
    const int Wl    = 96 >> lvl;
    const int start = 12288 - (12288 >> (2 * lvl));  // 0,9216,11520,12096
    const float fW  = (float)Wl;
    const int pil0  = (k & 1) << 1;              // point-in-level: 0 or 2

    const float* lq = loc + (size_t)q * 256 + h * 32 + lvl * 8 + pil0 * 2;
    float2 l01 = *(const float2*)lq;             // lx0, ly0   (8B aligned)
    float2 l23 = *(const float2*)(lq + 2);       // lx1, ly1
    float2 aw  = *(const float2*)(attn + (size_t)q * 128 + h * 16 + lvl * 4 + pil0);

    float wv[2][4]; int ov[2][4];
#pragma unroll
    for (int s = 0; s < 2; ++s) {
        float lx  = s ? l23.x : l01.x;
        float ly  = s ? l23.y : l01.y;
        float wgt = s ? aw.y  : aw.x;

        float x = lx * fW - 0.5f;
        float y = ly * fW - 0.5f;
        float xf = floorf(x), yf = floorf(y);
        float wx1 = x - xf, wy1 = y - yf;
        float wx0 = 1.f - wx1, wy0 = 1.f - wy1;
        int ix = (int)xf, iy = (int)yf;

        float wxv0 = ((unsigned)ix       < (unsigned)Wl) ? wx0 : 0.f;
        float wxv1 = ((unsigned)(ix + 1) < (unsigned)Wl) ? wx1 : 0.f;
        float wyv0 = (((unsigned)iy       < (unsigned)Wl) ? wy0 : 0.f) * wgt;
        float wyv1 = (((unsigned)(iy + 1) < (unsigned)Wl) ? wy1 : 0.f) * wgt;

        int ix0 = min(max(ix,     0), Wl - 1);
        int ix1 = min(max(ix + 1, 0), Wl - 1);
        int iy0 = min(max(iy,     0), Wl - 1);
        int iy1 = min(max(iy + 1, 0), Wl - 1);

        int r0 = start + iy0 * Wl, r1 = start + iy1 * Wl;
        wv[s][0] = wxv0 * wyv0;  ov[s][0] = (r0 + ix0) << 6;   // bytes: pix*64
        wv[s][1] = wxv1 * wyv0;  ov[s][1] = (r0 + ix1) << 6;
        wv[s][2] = wxv0 * wyv1;  ov[s][2] = (r1 + ix0) << 6;
        wv[s][3] = wxv1 * wyv1;  ov[s][3] = (r1 + ix1) << 6;
    }

    // ---- gather phase: all 16 points, data shared from owner lanes ----
    const char* planeB = (const char*)vt + (size_t)h * Lv * 64 + k * 8;
    float a0 = 0.f, a1 = 0.f, a2 = 0.f, a3 = 0.f;

    do_point< 0>(wv, ov, planeB, a0, a1, a2, a3);
    do_point< 1>(wv, ov, planeB, a0, a1, a2, a3);
    do_point< 2>(wv, ov, planeB, a0, a1, a2, a3);
    do_point< 3>(wv, ov, planeB, a0, a1, a2, a3);
    do_point< 4>(wv, ov, planeB, a0, a1, a2, a3);
    do_point< 5>(wv, ov, planeB, a0, a1, a2, a3);
    do_point< 6>(wv, ov, planeB, a0, a1, a2, a3);
    do_point< 7>(wv, ov, planeB, a0, a1, a2, a3);
    do_point< 8>(wv, ov, planeB, a0, a1, a2, a3);
    do_point< 9>(wv, ov, planeB, a0, a1, a2, a3);
    do_point<10>(wv, ov, planeB, a0, a1, a2, a3);
    do_point<11>(wv, ov, planeB, a0, a1, a2, a3);
    do_point<12>(wv, ov, planeB, a0, a1, a2, a3);
    do_point<13>(wv, ov, planeB, a0, a1, a2, a3);
    do_point<14>(wv, ov, planeB, a0, a1, a2, a3);
    do_point<15>(wv, ov, planeB, a0, a1, a2, a3);

    union { __hip_bfloat16 h4[4]; ushort4 u4; } st;
    st.h4[0] = __float2bfloat16(a0);
    st.h4[1] = __float2bfloat16(a1);
    st.h4[2] = __float2bfloat16(a2);
    st.h4[3] = __float2bfloat16(a3);
    *reinterpret_cast<ushort4*>(core + ((size_t)q * 256 + h * 32 + k * 4)) = st.u4;
}

// ---------------------------------------------------------------------------
extern "C" void kernel_launch(void* const* d_in, const int* in_sizes, int n_in,
                              void* d_out, int out_size, void* d_ws, size_t ws_size,
                              hipStream_t stream)
{
    const float* query  = (const float*)d_in[0];
    const float* refp   = (const float*)d_in[1];
    const float* value  = (const float*)d_in[2];
    const float* W_off  = (const float*)d_in[5];
    const float* b_off  = (const float*)d_in[6];
    const float* W_attn = (const float*)d_in[7];
    const float* b_attn = (const float*)d_in[8];
    const float* W_out  = (const float*)d_in[9];
    const float* b_out  = (const float*)d_in[10];
    float* out = (float*)d_out;

    const int M  = in_sizes[0] / D_MODEL;   // 12240
    const int Lv = in_sizes[2] / D_MODEL;   // 12240

    // workspace layout (~32 MB)
    float* loc  = (float*)d_ws;                                      // M*256 f32
    float* attn = loc + (size_t)M * 256;                             // M*128 f32
    __hip_bfloat16* qbf = (__hip_bfloat16*)(attn + (size_t)M * 128); // M*256 bf16
    __hip_bfloat16* wt  = qbf + (size_t)M * 256;                     // 640*256 bf16
    __hip_bfloat16* vt  = wt + 640 * 256;                            // 8*Lv*32 bf16
    __hip_bfloat16* core = qbf;   // alias: qbf dead after stage 1

    dim3 blk(256);
    const int mblocks = (M + 127) / 128;

    // Stage 0: bf16 conversion + weight pack + value head-major transpose
    int convthreads = M * 64 + 640 * 256 + Lv * 64;
    hipLaunchKernelGGL(convert_kernel, dim3((convthreads + 255) / 256), blk, 0, stream,
                       query, W_off, W_attn, W_out, value, qbf, wt, vt, M, Lv);

    // Stage 1: offsets+attention GEMM (N=384) with loc/softmax epilogue
    hipLaunchKernelGGL((gemm_mfma<1>), dim3(6, mblocks), blk, 0, stream,
                       qbf, wt, 0, b_off, b_attn, refp, loc, attn, M);

    // Stage 2: deformable bilinear sampling -> core (bf16, overwrites qbf)
    const int qchunks = (M + 31) / 32;
    hipLaunchKernelGGL(sample_kernel, dim3(qchunks * 8), blk, 0, stream,
                       loc, attn, vt, core, M, Lv);

    // Stage 3: output projection (N=256)
    hipLaunchKernelGGL((gemm_mfma<0>), dim3(4, mblocks), blk, 0, stream,
                       core, wt, 384, b_out, nullptr, nullptr, out, nullptr, M);
}

// Round 8
// 60.540 us; speedup vs baseline: 1.2349x; 1.1267x over previous
//
#include <hip/hip_runtime.h>
#include <hip/hip_bf16.h>
#include <math.h>

constexpr int D_MODEL  = 256;
constexpr int N_HEADS  = 8;

typedef __attribute__((ext_vector_type(8))) short bf16x8;
typedef __attribute__((ext_vector_type(4))) float f32x4;
typedef __attribute__((ext_vector_type(2))) float f32x2;

__device__ __forceinline__ void gld_lds16(const void* gsrc, void* ldst) {
    __builtin_amdgcn_global_load_lds(
        (const __attribute__((address_space(1))) unsigned int*)gsrc,
        (__attribute__((address_space(3))) unsigned int*)ldst, 16, 0, 0);
}

// ---------------------------------------------------------------------------
// Convert query -> bf16 [M][256]; pack W_off|W_attn|W_out transposed into
// Wt[640][256] bf16; transpose value -> vt[h][pix][32] BF16 (head-major).
// ---------------------------------------------------------------------------
__global__ __launch_bounds__(256) void convert_kernel(
    const float* __restrict__ q,
    const float* __restrict__ Woff,
    const float* __restrict__ Wattn,
    const float* __restrict__ Wout,
    const float* __restrict__ value,
    __hip_bfloat16* __restrict__ qbf,
    __hip_bfloat16* __restrict__ wt,
    __hip_bfloat16* __restrict__ vt,
    int M, int Lv)
{
    int t = blockIdx.x * 256 + threadIdx.x;
    int nq4 = M * 64;                       // float4 count of query
    if (t < nq4) {
        float4 v = reinterpret_cast<const float4*>(q)[t];
        union { __hip_bfloat16 h[4]; ushort4 u; } cv;
        cv.h[0] = __float2bfloat16(v.x);
        cv.h[1] = __float2bfloat16(v.y);
        cv.h[2] = __float2bfloat16(v.z);
        cv.h[3] = __float2bfloat16(v.w);
        reinterpret_cast<ushort4*>(qbf)[t] = cv.u;
        return;
    }
    int t2 = t - nq4;
    if (t2 < 640 * 256) {
        int c = t2 >> 8, k = t2 & 255;
        float val = (c < 256) ? Woff[k * 256 + c]
                  : (c < 384) ? Wattn[k * 128 + (c - 256)]
                              : Wout[k * 256 + (c - 384)];
        wt[c * 256 + k] = __float2bfloat16(val);
        return;
    }
    int t3 = t2 - 640 * 256;                // float4 index into value
    if (t3 < Lv * 64) {
        int pix = t3 >> 6;
        int c4  = (t3 & 63) * 4;            // channel 0..252 step 4
        int h   = c4 >> 5, d = c4 & 31;
        float4 v = reinterpret_cast<const float4*>(value)[t3];
        union { __hip_bfloat16 h4[4]; ushort4 u; } cv;
        cv.h4[0] = __float2bfloat16(v.x);
        cv.h4[1] = __float2bfloat16(v.y);
        cv.h4[2] = __float2bfloat16(v.z);
        cv.h4[3] = __float2bfloat16(v.w);
        *reinterpret_cast<ushort4*>(vt + (size_t)h * Lv * 32 + (size_t)pix * 32 + d) = cv.u;
    }
}

// ---------------------------------------------------------------------------
// bf16 MFMA GEMM (unchanged): BM=128, BN=64, BK=64, 4 waves, 16x16x32 bf16,
// global_load_lds staging with both-sides XOR swizzle.
// EPI=0: out0 = acc + ba.  EPI=1: n0<256 -> loc epilogue; else softmax.
// ---------------------------------------------------------------------------
template <int EPI>
__global__ __launch_bounds__(256) void gemm_mfma(
    const __hip_bfloat16* __restrict__ Abf,
    const __hip_bfloat16* __restrict__ Wt,
    int wrow0,
    const float* __restrict__ ba,
    const float* __restrict__ bb,
    const float* __restrict__ refpts,
    float* __restrict__ out0,
    float* __restrict__ out1,
    int M)
{
    __shared__ __align__(16) char smem[128 * 68 * 4];   // 34816B
    char*  A_lds = smem;            // [128 rows][128B]  (16KB)
    char*  B_lds = smem + 16384;    // [64 rows][128B]   (8KB)
    float* C_lds = (float*)smem;    // [128][68] f32 (unioned, post-loop)

    const int tid = threadIdx.x;
    const int w = tid >> 6, l = tid & 63;
    const int m0 = blockIdx.y * 128;
    const int n0 = blockIdx.x * 64;

    const char* Asrc = (const char*)Abf;                                  // 512B rows
    const char* Wsrc = (const char*)(Wt + (size_t)(wrow0 + n0) * 256);    // 512B rows

    f32x4 acc[2][4] = {};

    const int lr8 = l >> 3, l7 = l & 7;

    for (int k0 = 0; k0 < 512; k0 += 128) {
#pragma unroll
        for (int i = 0; i < 4; ++i) {
            int chunk = (w << 2) + i;
            int row = (chunk << 3) + lr8;
            int m = m0 + row; m = m < M ? m : (M - 1);
            gld_lds16(Asrc + (size_t)m * 512 + k0 + ((l7 ^ (row & 7)) << 4),
                      A_lds + (chunk << 10));
        }
#pragma unroll
        for (int i = 0; i < 2; ++i) {
            int chunk = (w << 1) + i;
            int row = (chunk << 3) + lr8;
            gld_lds16(Wsrc + (size_t)row * 512 + k0 + ((l7 ^ (row & 7)) << 4),
                      B_lds + (chunk << 10));
        }
        __syncthreads();

#pragma unroll
        for (int kk = 0; kk < 2; ++kk) {
            bf16x8 av[2], bv[4];
#pragma unroll
            for (int mf = 0; mf < 2; ++mf) {
                int arow = (w << 5) + (mf << 4) + (l & 15);
                int acb = ((kk << 6) + ((l >> 4) << 4)) ^ ((arow & 7) << 4);
                av[mf] = *(const bf16x8*)(A_lds + arow * 128 + acb);
            }
#pragma unroll
            for (int nf = 0; nf < 4; ++nf) {
                int brow = (nf << 4) + (l & 15);
                int bcb = ((kk << 6) + ((l >> 4) << 4)) ^ ((brow & 7) << 4);
                bv[nf] = *(const bf16x8*)(B_lds + brow * 128 + bcb);
            }
#pragma unroll
            for (int mf = 0; mf < 2; ++mf)
#pragma unroll
                for (int nf = 0; nf < 4; ++nf)
                    acc[mf][nf] = __builtin_amdgcn_mfma_f32_16x16x32_bf16(
                        av[mf], bv[nf], acc[mf][nf], 0, 0, 0);
        }
        __syncthreads();
    }

#pragma unroll
    for (int mf = 0; mf < 2; ++mf)
#pragma unroll
        for (int nf = 0; nf < 4; ++nf) {
            int col = (nf << 4) + (l & 15);
            int rbase = (w << 5) + (mf << 4) + ((l >> 4) << 2);
#pragma unroll
            for (int j = 0; j < 4; ++j)
                C_lds[(rbase + j) * 68 + col] = acc[mf][nf][j];
        }
    __syncthreads();

    if (EPI == 0 || n0 < 256) {
#pragma unroll
        for (int r2 = 0; r2 < 2; ++r2) {
            int row = (r2 << 6) + (tid >> 2);
            int q = m0 + row;
            if (q >= M) continue;
            float rx = 0.f, ry = 0.f;
            if (EPI == 1) { rx = refpts[q * 2]; ry = refpts[q * 2 + 1]; }
#pragma unroll
            for (int g = 0; g < 4; ++g) {
                int col = ((tid & 3) << 4) + (g << 2);
                float4 v  = *(float4*)&C_lds[row * 68 + col];
                float4 b4 = *(const float4*)&ba[n0 + col];
                if (EPI == 0) {
                    v.x += b4.x; v.y += b4.y; v.z += b4.z; v.w += b4.w;
                } else {
                    int c = n0 + col;                        // h*32+l*8+p*2+xy
                    float rn = 1.0f / (float)(96 >> ((c >> 3) & 3));
                    v.x = rx + (v.x + b4.x) * rn;
                    v.y = ry + (v.y + b4.y) * rn;
                    v.z = rx + (v.z + b4.z) * rn;
                    v.w = ry + (v.w + b4.w) * rn;
                }
                *(float4*)&out0[(size_t)q * 256 + n0 + col] = v;
            }
        }
    } else {
        for (int u = tid; u < 512; u += 256) {
            int row = u >> 2, hh = u & 3;
            int q = m0 + row;
            if (q >= M) continue;
            int cg = (n0 - 256) + (hh << 4);
            float s[16];
            float mx = -1e30f;
#pragma unroll
            for (int i = 0; i < 16; ++i) {
                s[i] = C_lds[row * 68 + (hh << 4) + i] + bb[cg + i];
                mx = fmaxf(mx, s[i]);
            }
            float sum = 0.f;
#pragma unroll
            for (int i = 0; i < 16; ++i) { s[i] = __expf(s[i] - mx); sum += s[i]; }
            float inv = 1.0f / sum;
#pragma unroll
            for (int g = 0; g < 4; ++g) {
                float4 v = make_float4(s[g*4]*inv, s[g*4+1]*inv, s[g*4+2]*inv, s[g*4+3]*inv);
                *(float4*)&out1[(size_t)q * 128 + cg + (g << 2)] = v;
            }
        }
    }
}

// ---------------------------------------------------------------------------
// ds_swizzle helpers (template immediates — frontend requires ICE).
// ---------------------------------------------------------------------------
template <int IMM>
__device__ __forceinline__ float swzf(float v) {
    return __int_as_float(__builtin_amdgcn_ds_swizzle(__float_as_int(v), IMM));
}
template <int IMM>
__device__ __forceinline__ int swzi(int v) {
    return __builtin_amdgcn_ds_swizzle(v, IMM);
}

// bf16 pair (one dword) -> f32x2 via shift/mask (no cvt instruction)
__device__ __forceinline__ f32x2 bf2(unsigned v) {
    f32x2 r;
    r.x = __uint_as_float(v << 16);
    r.y = __uint_as_float(v & 0xffff0000u);
    return r;
}
__device__ __forceinline__ unsigned packbf(float lo, float hi) {
    __hip_bfloat16 a = __float2bfloat16(lo), b = __float2bfloat16(hi);
    return (unsigned)*(unsigned short*)&a | ((unsigned)*(unsigned short*)&b << 16);
}

// One sampling point P (0..15) for 4-lane units. Owner lane = P>>2 (= level),
// owner-local point index S = P&3. Bit-mode swizzle: and=0x1C keeps lane
// bits[4:2] (unit id), or=owner sets bits[1:0]. Corner = uint4 (8 bf16 dims).
template <int P>
__device__ __forceinline__ void do_point4(
    const float wv[4][4], const int ov[4][4], const char* planeB,
    f32x2& a0, f32x2& a1, f32x2& a2, f32x2& a3)
{
    constexpr int S   = P & 3;
    constexpr int IMM = ((P >> 2) << 5) | 0x1C;

    float w00 = swzf<IMM>(wv[S][0]);
    float w10 = swzf<IMM>(wv[S][1]);
    float w01 = swzf<IMM>(wv[S][2]);
    float w11 = swzf<IMM>(wv[S][3]);
    int o00 = swzi<IMM>(ov[S][0]);
    int o10 = swzi<IMM>(ov[S][1]);
    int o01 = swzi<IMM>(ov[S][2]);
    int o11 = swzi<IMM>(ov[S][3]);

    uint4 u0 = *(const uint4*)(planeB + o00);
    uint4 u1 = *(const uint4*)(planeB + o10);
    uint4 u2 = *(const uint4*)(planeB + o01);
    uint4 u3 = *(const uint4*)(planeB + o11);

    { f32x2 w2 = {w00, w00};
      a0 += bf2(u0.x) * w2; a1 += bf2(u0.y) * w2;
      a2 += bf2(u0.z) * w2; a3 += bf2(u0.w) * w2; }
    { f32x2 w2 = {w10, w10};
      a0 += bf2(u1.x) * w2; a1 += bf2(u1.y) * w2;
      a2 += bf2(u1.z) * w2; a3 += bf2(u1.w) * w2; }
    { f32x2 w2 = {w01, w01};
      a0 += bf2(u2.x) * w2; a1 += bf2(u2.y) * w2;
      a2 += bf2(u2.z) * w2; a3 += bf2(u2.w) * w2; }
    { f32x2 w2 = {w11, w11};
      a0 += bf2(u3.x) * w2; a1 += bf2(u3.y) * w2;
      a2 += bf2(u3.z) * w2; a3 += bf2(u3.w) * w2; }
}

// ---------------------------------------------------------------------------
// Deformable bilinear sampling v4: 4-lane units.
// Unit = 4 lanes = one (q,h); lane j owns 8 dims (uint4/corner, 16B) AND is
// the coordinate owner for level j (all 4 of its points). Swizzle insts and
// VMEM insts per unit halve vs the 8-lane version; bytes unchanged.
// ---------------------------------------------------------------------------
__global__ __launch_bounds__(256, 4) void sample_kernel(
    const float* __restrict__ loc,
    const float* __restrict__ attn,
    const __hip_bfloat16* __restrict__ vt, // [8][Lv][32] bf16, head-major
    __hip_bfloat16* __restrict__ core,     // [M][256] bf16
    int M, int Lv)
{
    const int h  = blockIdx.x & 7;
    const int q0 = (blockIdx.x >> 3) << 6;       // 64 q's per block
    const int u_ = threadIdx.x >> 2;             // unit in block, 0..63
    const int j  = threadIdx.x & 3;              // lane-in-unit = level
    const int q  = q0 + u_;
    if (q >= M) return;                          // whole 4-lane units exit

    // ---- owner phase: lane j computes all 4 points of level j ----
    const int Wl    = 96 >> j;
    const int start = 12288 - (12288 >> (2 * j));    // 0,9216,11520,12096
    const float fW  = (float)Wl;

    const float4* lq4 = (const float4*)(loc + (size_t)q * 256 + h * 32 + j * 8);
    float4 pa = lq4[0];                          // p0.x p0.y p1.x p1.y
    float4 pb = lq4[1];                          // p2.x p2.y p3.x p3.y
    float4 aw = *(const float4*)(attn + (size_t)q * 128 + h * 16 + j * 4);

    const float lxs[4] = {pa.x, pa.z, pb.x, pb.z};
    const float lys[4] = {pa.y, pa.w, pb.y, pb.w};
    const float aws[4] = {aw.x, aw.y, aw.z, aw.w};

    float wv[4][4]; int ov[4][4];
#pragma unroll
    for (int s = 0; s < 4; ++s) {
        float x = lxs[s] * fW - 0.5f;
        float y = lys[s] * fW - 0.5f;
        float wgt = aws[s];

        float xf = floorf(x), yf = floorf(y);
        float wx1 = x - xf, wy1 = y - yf;
        float wx0 = 1.f - wx1, wy0 = 1.f - wy1;
        int ix = (int)xf, iy = (int)yf;

        float wxv0 = ((unsigned)ix       < (unsigned)Wl) ? wx0 : 0.f;
        float wxv1 = ((unsigned)(ix + 1) < (unsigned)Wl) ? wx1 : 0.f;
        float wyv0 = (((unsigned)iy       < (unsigned)Wl) ? wy0 : 0.f) * wgt;
        float wyv1 = (((unsigned)(iy + 1) < (unsigned)Wl) ? wy1 : 0.f) * wgt;

        int ix0 = min(max(ix,     0), Wl - 1);
        int ix1 = min(max(ix + 1, 0), Wl - 1);
        int iy0 = min(max(iy,     0), Wl - 1);
        int iy1 = min(max(iy + 1, 0), Wl - 1);

        int r0 = start + iy0 * Wl, r1 = start + iy1 * Wl;
        wv[s][0] = wxv0 * wyv0;  ov[s][0] = (r0 + ix0) << 6;   // bytes: pix*64
        wv[s][1] = wxv1 * wyv0;  ov[s][1] = (r0 + ix1) << 6;
        wv[s][2] = wxv0 * wyv1;  ov[s][2] = (r1 + ix0) << 6;
        wv[s][3] = wxv1 * wyv1;  ov[s][3] = (r1 + ix1) << 6;
    }

    // ---- gather phase: 16 points, coords pulled from owner lanes ----
    const char* planeB = (const char*)vt + (size_t)h * Lv * 64 + j * 16;
    f32x2 a0 = {0.f, 0.f}, a1 = a0, a2 = a0, a3 = a0;

    do_point4< 0>(wv, ov, planeB, a0, a1, a2, a3);
    do_point4< 1>(wv, ov, planeB, a0, a1, a2, a3);
    do_point4< 2>(wv, ov, planeB, a0, a1, a2, a3);
    do_point4< 3>(wv, ov, planeB, a0, a1, a2, a3);
    do_point4< 4>(wv, ov, planeB, a0, a1, a2, a3);
    do_point4< 5>(wv, ov, planeB, a0, a1, a2, a3);
    do_point4< 6>(wv, ov, planeB, a0, a1, a2, a3);
    do_point4< 7>(wv, ov, planeB, a0, a1, a2, a3);
    do_point4< 8>(wv, ov, planeB, a0, a1, a2, a3);
    do_point4< 9>(wv, ov, planeB, a0, a1, a2, a3);
    do_point4<10>(wv, ov, planeB, a0, a1, a2, a3);
    do_point4<11>(wv, ov, planeB, a0, a1, a2, a3);
    do_point4<12>(wv, ov, planeB, a0, a1, a2, a3);
    do_point4<13>(wv, ov, planeB, a0, a1, a2, a3);
    do_point4<14>(wv, ov, planeB, a0, a1, a2, a3);
    do_point4<15>(wv, ov, planeB, a0, a1, a2, a3);

    // ---- store dims j*8 .. j*8+7 (16B) ----
    uint4 st;
    st.x = packbf(a0.x, a0.y);
    st.y = packbf(a1.x, a1.y);
    st.z = packbf(a2.x, a2.y);
    st.w = packbf(a3.x, a3.y);
    *(uint4*)((char*)core + ((size_t)q * 256 + h * 32 + j * 8) * 2) = st;
}

// ---------------------------------------------------------------------------
extern "C" void kernel_launch(void* const* d_in, const int* in_sizes, int n_in,
                              void* d_out, int out_size, void* d_ws, size_t ws_size,
                              hipStream_t stream)
{
    const float* query  = (const float*)d_in[0];
    const float* refp   = (const float*)d_in[1];
    const float* value  = (const float*)d_in[2];
    const float* W_off  = (const float*)d_in[5];
    const float* b_off  = (const float*)d_in[6];
    const float* W_attn = (const float*)d_in[7];
    const float* b_attn = (const float*)d_in[8];
    const float* W_out  = (const float*)d_in[9];
    const float* b_out  = (const float*)d_in[10];
    float* out = (float*)d_out;

    const int M  = in_sizes[0] / D_MODEL;   // 12240
    const int Lv = in_sizes[2] / D_MODEL;   // 12240

    // workspace layout (~32 MB)
    float* loc  = (float*)d_ws;                                      // M*256 f32
    float* attn = loc + (size_t)M * 256;                             // M*128 f32
    __hip_bfloat16* qbf = (__hip_bfloat16*)(attn + (size_t)M * 128); // M*256 bf16
    __hip_bfloat16* wt  = qbf + (size_t)M * 256;                     // 640*256 bf16
    __hip_bfloat16* vt  = wt + 640 * 256;                            // 8*Lv*32 bf16
    __hip_bfloat16* core = qbf;   // alias: qbf dead after stage 1

    dim3 blk(256);
    const int mblocks = (M + 127) / 128;

    // Stage 0: bf16 conversion + weight pack + value head-major transpose
    int convthreads = M * 64 + 640 * 256 + Lv * 64;
    hipLaunchKernelGGL(convert_kernel, dim3((convthreads + 255) / 256), blk, 0, stream,
                       query, W_off, W_attn, W_out, value, qbf, wt, vt, M, Lv);

    // Stage 1: offsets+attention GEMM (N=384) with loc/softmax epilogue
    hipLaunchKernelGGL((gemm_mfma<1>), dim3(6, mblocks), blk, 0, stream,
                       qbf, wt, 0, b_off, b_attn, refp, loc, attn, M);

    // Stage 2: deformable bilinear sampling -> core (bf16, overwrites qbf)
    const int qchunks = (M + 63) / 64;
    hipLaunchKernelGGL(sample_kernel, dim3(qchunks * 8), blk, 0, stream,
                       loc, attn, vt, core, M, Lv);

    // Stage 3: output projection (N=256)
    hipLaunchKernelGGL((gemm_mfma<0>), dim3(4, mblocks), blk, 0, stream,
                       core, wt, 384, b_out, nullptr, nullptr, out, nullptr, M);
}